// Round 1
// baseline (169.724 us; speedup 1.0000x reference)
//
#include <hip/hip_runtime.h>

// Problem constants (from reference):
//   confidence_maps: (8, 6, 4, 512, 512) f32
//   warp_masks:      (8, 1, 512, 512)    f32
//   gauss_kernel:    (1, 1, 5, 5)        f32
// Output: mask (48, 1, 512, 512) f32  +  rate scalar f32  => 12,582,913 floats.
//
// Key simplifications:
//  - rate == 0.5 exactly (top_k picks exactly K=HW/2 distinct indices per row).
//  - rows with l==0 are forced to 1.0 and don't affect rate -> no compute.
//  - max_c(sigmoid(x_c)) == sigmoid(max_c(x_c)) (monotone) -> 1 sigmoid/pixel.
//  - all smoothing math in double so the mask matches the numpy f64 reference
//    bit-for-bit at the top-K boundary (f32 noise ~1e-7 vs order-stat spacing
//    ~4e-7 would risk single-bit mask flips => absmax 1.0 fail).

#define NROWSEL 40            // rows with l != 0 (b in 0..7, l in 1..5)
#define NPIX    262144        // 512*512
#define KSEL    131072u       // int(HW * 0.5)
#define CAND_CAP 8192

// ---- workspace layout (bytes) ----
#define OFF_SM   0ull                          // 40*262144 doubles = 83,886,080
#define OFF_H1   83886080ull                   // 40*2048 u32       =    327,680
#define OFF_H2   84213760ull                   // 40*2048 u32       =    327,680
#define OFF_ST   84541440ull                   // 40*4 int          =        640
#define OFF_CC   84542080ull                   // 40 u32            =        160
#define OFF_CV   84542240ull                   // 40*8192 double    =  2,621,440
#define OFF_CI   87163680ull                   // 40*8192 int       =  1,310,720
#define META_BYTES (OFF_CV - OFF_H1)           // zero hist1,hist2,state,counts

__device__ __forceinline__ unsigned qkey(double v) {
  // monotone non-decreasing 32-bit key for v in [0,1); ties resolved later
  double t = v * 4294967296.0;
  t = fmax(t, 0.0);
  t = fmin(t, 4294967295.0);
  return (unsigned)t;
}

// Fill the 8 ego rows (l==0) with 1.0
__global__ void ego_fill_kernel(float* __restrict__ out) {
  int i = blockIdx.x * 256 + threadIdx.x;       // 0 .. 524287 (float4 units)
  int b = i >> 16;                               // 65536 float4 per row
  int o4 = i & 65535;
  float4* p = (float4*)(out + (size_t)b * 6u * NPIX) + o4;
  *p = make_float4(1.f, 1.f, 1.f, 1.f);
}

// Fused: m = sigmoid(max_c conf)*warp (f64), 5x5 gaussian conv, store sm (f64),
// and first-level histogram of key bits [31:21].
__global__ __launch_bounds__(256) void compute_kernel(
    const float* __restrict__ conf, const float* __restrict__ warp,
    const float* __restrict__ gk, double* __restrict__ sm,
    unsigned* __restrict__ hist1) {
  const int blk = blockIdx.x;        // NROWSEL * 64
  const int j = blk >> 6;            // selected-row index 0..39
  const int tile = blk & 63;         // 8x8 tiles of 64x64
  const int ty0 = (tile >> 3) << 6;
  const int tx0 = (tile & 7) << 6;
  const int b = j / 5;
  const int l = j % 5 + 1;
  const int rowg = b * 6 + l;
  const float* confr = conf + (size_t)rowg * 4u * NPIX;
  const float* warpr = warp + (size_t)b * NPIX;

  __shared__ double mt[68][69];
  __shared__ double g[25];
  __shared__ unsigned lh[2048];
  const int tid = threadIdx.x;
  if (tid < 25) g[tid] = (double)gk[tid];
  for (int i = tid; i < 2048; i += 256) lh[i] = 0u;

  // load 68x68 halo of m
  for (int i = tid; i < 68 * 68; i += 256) {
    int hy = i / 68, hx = i % 68;
    int gy = ty0 + hy - 2, gx = tx0 + hx - 2;
    double m = 0.0;
    if (gy >= 0 && gy < 512 && gx >= 0 && gx < 512) {
      int off = gy * 512 + gx;
      float x0 = confr[off];
      float x1 = confr[NPIX + off];
      float x2 = confr[2 * NPIX + off];
      float x3 = confr[3 * NPIX + off];
      float mx = fmaxf(fmaxf(x0, x1), fmaxf(x2, x3));
      double s = 1.0 / (1.0 + exp(-(double)mx));   // f64 sigmoid
      m = s * (double)warpr[off];
    }
    mt[hy][hx] = m;
  }
  __syncthreads();

  const int txl = tid & 63;
  const int tyl = tid >> 6;           // 0..3
  double* smrow = sm + (size_t)j * NPIX;
  for (int rr = 0; rr < 16; ++rr) {
    int yy = tyl + (rr << 2);         // 0..63
    double acc = 0.0;
#pragma unroll
    for (int dy = 0; dy < 5; ++dy)
#pragma unroll
      for (int dx = 0; dx < 5; ++dx)
        acc += g[dy * 5 + dx] * mt[yy + dy][txl + dx];
    smrow[(ty0 + yy) * 512 + (tx0 + txl)] = acc;
    atomicAdd(&lh[qkey(acc) >> 21], 1u);
  }
  __syncthreads();
  unsigned* h1 = hist1 + j * 2048;
  for (int i = tid; i < 2048; i += 256)
    if (lh[i]) atomicAdd(&h1[i], lh[i]);
}

// Find bin b1 (descending) where cumulative count crosses KSEL; A1 = count above.
__global__ void scan1_kernel(const unsigned* __restrict__ hist1,
                             int* __restrict__ st) {
  int j = blockIdx.x;
  const unsigned* h = hist1 + j * 2048;
  __shared__ unsigned cs[256];
  int tid = threadIdx.x;
  unsigned s = 0;
  for (int k = 0; k < 8; ++k) s += h[tid * 8 + k];
  cs[tid] = s;
  __syncthreads();
  if (tid == 0) {
    unsigned cum = 0; int b1 = 0; unsigned A1 = 0;
    for (int c = 255; c >= 0; --c) {
      if (cum + cs[c] >= KSEL) {
        unsigned cc = cum;
        for (int k = 7; k >= 0; --k) {
          unsigned hv = h[c * 8 + k];
          if (cc + hv >= KSEL) { b1 = c * 8 + k; A1 = cc; break; }
          cc += hv;
        }
        break;
      }
      cum += cs[c];
    }
    st[j * 4 + 0] = b1;
    st[j * 4 + 1] = (int)A1;
  }
}

// Second-level histogram of key bits [20:10] for elements in bin b1.
__global__ __launch_bounds__(256) void hist2_kernel(
    const double* __restrict__ sm, const int* __restrict__ st,
    unsigned* __restrict__ hist2) {
  int blk = blockIdx.x;
  int j = blk >> 6, seg = blk & 63;
  unsigned b1 = (unsigned)st[j * 4 + 0];
  const double* s = sm + (size_t)j * NPIX + seg * 4096;
  __shared__ unsigned lh[2048];
  for (int i = threadIdx.x; i < 2048; i += 256) lh[i] = 0u;
  __syncthreads();
  for (int it = 0; it < 16; ++it) {
    unsigned key = qkey(s[threadIdx.x + it * 256]);
    if ((key >> 21) == b1) atomicAdd(&lh[(key >> 10) & 2047u], 1u);
  }
  __syncthreads();
  unsigned* h2 = hist2 + j * 2048;
  for (int i = threadIdx.x; i < 2048; i += 256)
    if (lh[i]) atomicAdd(&h2[i], lh[i]);
}

// Within bin b1, find sub-bin b2; A2 = total count strictly above prefix (b1,b2).
__global__ void scan2_kernel(const unsigned* __restrict__ hist2,
                             int* __restrict__ st) {
  int j = blockIdx.x;
  const unsigned* h = hist2 + j * 2048;
  __shared__ unsigned cs[256];
  int tid = threadIdx.x;
  unsigned s = 0;
  for (int k = 0; k < 8; ++k) s += h[tid * 8 + k];
  cs[tid] = s;
  __syncthreads();
  if (tid == 0) {
    unsigned A1 = (unsigned)st[j * 4 + 1];
    unsigned cum = A1; int b2 = 0; unsigned A2 = A1;
    for (int c = 255; c >= 0; --c) {
      if (cum + cs[c] >= KSEL) {
        unsigned cc = cum;
        for (int k = 7; k >= 0; --k) {
          unsigned hv = h[c * 8 + k];
          if (cc + hv >= KSEL) { b2 = c * 8 + k; A2 = cc; break; }
          cc += hv;
        }
        break;
      }
      cum += cs[c];
    }
    st[j * 4 + 2] = b2;
    st[j * 4 + 3] = (int)A2;
  }
}

// Write mask for decided elements; gather cutoff-prefix candidates.
__global__ __launch_bounds__(256) void mask_gather_kernel(
    const double* __restrict__ sm, const int* __restrict__ st,
    float* __restrict__ out, unsigned* __restrict__ ccount,
    double* __restrict__ cval, int* __restrict__ cidx) {
  int blk = blockIdx.x;
  int j = blk >> 6, seg = blk & 63;
  int b = j / 5, l = j % 5 + 1;
  int rowg = b * 6 + l;
  unsigned b1 = (unsigned)st[j * 4 + 0];
  unsigned b2 = (unsigned)st[j * 4 + 2];
  unsigned pstar = (b1 << 11) | b2;
  const double* s = sm + (size_t)j * NPIX + seg * 4096;
  float* o = out + (size_t)rowg * NPIX + seg * 4096;
  for (int it = 0; it < 16; ++it) {
    int i = threadIdx.x + it * 256;
    double v = s[i];
    unsigned p = qkey(v) >> 10;
    float mv = 0.0f;
    if (p > pstar) {
      mv = 1.0f;
    } else if (p == pstar) {
      unsigned slot = atomicAdd(&ccount[j], 1u);
      if (slot < CAND_CAP) {
        cval[j * CAND_CAP + slot] = v;
        cidx[j * CAND_CAP + slot] = seg * 4096 + i;
      }
    }
    o[i] = mv;
  }
}

// Exact rank among candidates: take R = K - A2 largest by (value desc, idx asc).
__global__ void finalize_kernel(const int* __restrict__ st,
                                const unsigned* __restrict__ ccount,
                                const double* __restrict__ cval,
                                const int* __restrict__ cidx,
                                float* __restrict__ out) {
  int j = blockIdx.x;
  int b = j / 5, l = j % 5 + 1;
  int rowg = b * 6 + l;
  unsigned A2 = (unsigned)st[j * 4 + 3];
  int R = (int)(KSEL - A2);
  int C = (int)min(ccount[j], (unsigned)CAND_CAP);
  const double* v = cval + j * CAND_CAP;
  const int* id = cidx + j * CAND_CAP;
  for (int i = threadIdx.x; i < C; i += 256) {
    double vi = v[i];
    int ii = id[i];
    int rank = 0;
    for (int q = 0; q < C; ++q) {
      double vq = v[q];
      rank += (vq > vi) || (vq == vi && id[q] < ii) ? 1 : 0;
    }
    if (rank < R) out[(size_t)rowg * NPIX + ii] = 1.0f;
  }
  if (j == 0 && threadIdx.x == 0) out[12582912] = 0.5f;  // rate == 0.5 exactly
}

extern "C" void kernel_launch(void* const* d_in, const int* in_sizes, int n_in,
                              void* d_out, int out_size, void* d_ws, size_t ws_size,
                              hipStream_t stream) {
  const float* conf = (const float*)d_in[0];
  const float* warp = (const float*)d_in[1];
  const float* gk   = (const float*)d_in[2];
  float* out = (float*)d_out;
  char* ws = (char*)d_ws;

  double*   sm = (double*)(ws + OFF_SM);
  unsigned* h1 = (unsigned*)(ws + OFF_H1);
  unsigned* h2 = (unsigned*)(ws + OFF_H2);
  int*      st = (int*)(ws + OFF_ST);
  unsigned* cc = (unsigned*)(ws + OFF_CC);
  double*   cv = (double*)(ws + OFF_CV);
  int*      ci = (int*)(ws + OFF_CI);

  hipMemsetAsync(ws + OFF_H1, 0, (size_t)META_BYTES, stream);

  ego_fill_kernel<<<2048, 256, 0, stream>>>(out);
  compute_kernel<<<NROWSEL * 64, 256, 0, stream>>>(conf, warp, gk, sm, h1);
  scan1_kernel<<<NROWSEL, 256, 0, stream>>>(h1, st);
  hist2_kernel<<<NROWSEL * 64, 256, 0, stream>>>(sm, st, h2);
  scan2_kernel<<<NROWSEL, 256, 0, stream>>>(h2, st);
  mask_gather_kernel<<<NROWSEL * 64, 256, 0, stream>>>(sm, st, out, cc, cv, ci);
  finalize_kernel<<<NROWSEL, 256, 0, stream>>>(st, cc, cv, ci, out);
}